// Round 1
// baseline (602.826 us; speedup 1.0000x reference)
//
#include <hip/hip_runtime.h>

#define AS1 __attribute__((address_space(1)))
#define AS3 __attribute__((address_space(3)))

typedef unsigned short u16;
typedef short s16x8 __attribute__((ext_vector_type(8)));
typedef float f32x4 __attribute__((ext_vector_type(4)));

__device__ __forceinline__ float bf2f(u16 u) {
    union { unsigned u; float f; } v; v.u = ((unsigned)u) << 16; return v.f;
}
__device__ __forceinline__ u16 f2bf(float f) {
    union { float f; unsigned u; } v; v.f = f;
    unsigned u = v.u;
    return (u16)((u + 0x7FFFu + ((u >> 16) & 1u)) >> 16);
}

__device__ __forceinline__ void gload16(const void* g, void* l) {
    __builtin_amdgcn_global_load_lds((const AS1 void*)g, (AS3 void*)l, 16, 0, 0);
}

// ---------------------------------------------------------------- transpose+cvt
// src: (R x C) f32, dst: (C x R) bf16
__global__ __launch_bounds__(256) void transpose_bf16(
    const float* __restrict__ src, u16* __restrict__ dst, int R, int C)
{
    __shared__ float t[32][33];
    const int tx = threadIdx.x, ty = threadIdx.y;
    const int r0 = blockIdx.x * 32, c0 = blockIdx.y * 32;
#pragma unroll
    for (int i = 0; i < 4; i++)
        t[ty + i * 8][tx] = src[(size_t)(r0 + ty + i * 8) * C + c0 + tx];
    __syncthreads();
#pragma unroll
    for (int i = 0; i < 4; i++)
        dst[(size_t)(c0 + ty + i * 8) * R + r0 + tx] = f2bf(t[tx][ty + i * 8]);
}

// ---------------------------------------------------------------- layernorm -> bf16
__global__ __launch_bounds__(256) void ln_bf16(
    const float* __restrict__ x, const float* __restrict__ w,
    const float* __restrict__ b, u16* __restrict__ out)
{
    __shared__ float red[8];
    const int row = blockIdx.x;
    const int tid = threadIdx.x;
    const size_t base = (size_t)row * 1024 + tid * 4;
    const float4 xv = *(const float4*)&x[base];
    float s = xv.x + xv.y + xv.z + xv.w;
    float q = xv.x * xv.x + xv.y * xv.y + xv.z * xv.z + xv.w * xv.w;
#pragma unroll
    for (int m = 1; m < 64; m <<= 1) { s += __shfl_xor(s, m); q += __shfl_xor(q, m); }
    if ((tid & 63) == 0) { red[tid >> 6] = s; red[4 + (tid >> 6)] = q; }
    __syncthreads();
    s = red[0] + red[1] + red[2] + red[3];
    q = red[4] + red[5] + red[6] + red[7];
    const float mu = s * (1.f / 1024.f);
    const float var = q * (1.f / 1024.f) - mu * mu;
    const float rs = rsqrtf(var + 1e-5f);
    const float4 wv = *(const float4*)&w[tid * 4];
    const float4 bv = *(const float4*)&b[tid * 4];
    uint2 ov;
    ov.x = (unsigned)f2bf((xv.x - mu) * rs * wv.x + bv.x) |
           ((unsigned)f2bf((xv.y - mu) * rs * wv.y + bv.y) << 16);
    ov.y = (unsigned)f2bf((xv.z - mu) * rs * wv.z + bv.z) |
           ((unsigned)f2bf((xv.w - mu) * rs * wv.w + bv.w) << 16);
    *(uint2*)&out[base] = ov;
}

// ---------------------------------------------------------------- bf16 MFMA GEMM, B^T
// EP: 0 = f32; 1 = bf16; 2 = f32 +resid; 3 = bf16 gelu(acc+bias); 4 = f32 +bias+resid
template <int EP>
__global__ __launch_bounds__(256, 2) void gemm_bt(
    const u16* __restrict__ A, const u16* __restrict__ BT,
    float* __restrict__ Cf, u16* __restrict__ Cb,
    const float* __restrict__ bias, const float* __restrict__ resid,
    int M, int N, int K)
{
    __shared__ u16 As[4096];
    __shared__ u16 Bs[4096];
    const int tid = threadIdx.x;
    const int w = tid >> 6;
    const int l = tid & 63;
    const int tm = blockIdx.x * 128;
    const int tn = blockIdx.y * 128;
    const int wm = (w >> 1) * 64;
    const int wn = (w & 1) * 64;

    f32x4 acc[4][4] = {};

    const int e0 = w * 512 + l * 8;
    const int r0 = e0 >> 5, c0 = e0 & 31;
    const int e1 = 2048 + e0;
    const int r1 = e1 >> 5, c1 = e1 & 31;
    const size_t arow0 = (size_t)(tm + r0) * K + c0;
    const size_t arow1 = (size_t)(tm + r1) * K + c1;
    const size_t brow0 = (size_t)(tn + r0) * K + c0;
    const size_t brow1 = (size_t)(tn + r1) * K + c1;
    const int lofs = w * 512;         // wave-uniform LDS base (ushorts)
    const int afr = wm + (l & 15);
    const int bfr = wn + (l & 15);
    const int kk = (l >> 4) * 8;

    for (int k0 = 0; k0 < K; k0 += 32) {
        gload16(&A[arow0 + k0], &As[lofs]);
        gload16(&A[arow1 + k0], &As[2048 + lofs]);
        gload16(&BT[brow0 + k0], &Bs[lofs]);
        gload16(&BT[brow1 + k0], &Bs[2048 + lofs]);
        __syncthreads();
        s16x8 a[4], b[4];
#pragma unroll
        for (int i = 0; i < 4; i++) a[i] = *(const s16x8*)&As[(afr + i * 16) * 32 + kk];
#pragma unroll
        for (int j = 0; j < 4; j++) b[j] = *(const s16x8*)&Bs[(bfr + j * 16) * 32 + kk];
#pragma unroll
        for (int i = 0; i < 4; i++)
#pragma unroll
            for (int j = 0; j < 4; j++)
                acc[i][j] = __builtin_amdgcn_mfma_f32_16x16x32_bf16(a[i], b[j], acc[i][j], 0, 0, 0);
        __syncthreads();
    }

    const int erow = tm + wm + (l >> 4) * 4;
    const int ecol = tn + wn + (l & 15);
#pragma unroll
    for (int i = 0; i < 4; i++) {
#pragma unroll
        for (int j = 0; j < 4; j++) {
            const int col = ecol + j * 16;
#pragma unroll
            for (int r = 0; r < 4; r++) {
                const int row = erow + i * 16 + r;
                const size_t idx = (size_t)row * N + col;
                const float v = acc[i][j][r];
                if (EP == 0) {
                    Cf[idx] = v;
                } else if (EP == 1) {
                    Cb[idx] = f2bf(v);
                } else if (EP == 2) {
                    Cf[idx] = v + resid[idx];
                } else if (EP == 3) {
                    const float u = v + bias[col];
                    Cb[idx] = f2bf(0.5f * u * (1.f + erff(u * 0.70710678118654752f)));
                } else {
                    Cf[idx] = v + bias[col] + resid[idx];
                }
            }
        }
    }
}

// ---------------------------------------------------------------- GLA per-chunk (parallel)
#define LDP 65
__global__ __launch_bounds__(256) void gla_a(
    const u16* __restrict__ qkv,     // (8192,3072) bf16: q|k|v col-blocks of 1024 (h*64+d)
    const float* __restrict__ g,     // (8192,1024) f32 gate logits
    const float* __restrict__ bg,    // (1024)
    u16* __restrict__ qdec,          // [bh][4096][64] bf16
    float* __restrict__ kvout,       // [bh][64][64][64]  (chunk, d, e)
    float* __restrict__ cdec,        // [bh][64][64]
    float* __restrict__ ointra)      // [bh][4096][64]
{
    __shared__ float qs[64 * LDP], ks[64 * LDP], vs[64 * LDP], la[64 * LDP];
    __shared__ float lm[64], nqi[64], nki[64];
    const int bid = blockIdx.x;
    const int bh = bid >> 6, ck = bid & 63;
    const int b = bh >> 4, h = bh & 15;
    const int tok0 = b * 4096 + ck * 64;
    const int tid = threadIdx.x;
    const int c = tid >> 2, gq = tid & 3;

    {   // load q,k,v bf16 and compute log-alpha (fp32 gate path)
        const size_t rb = (size_t)(tok0 + c) * 3072 + h * 64 + gq * 16;
#pragma unroll
        for (int u = 0; u < 2; u++) {
            uint4 qv = *(const uint4*)&qkv[rb + u * 8];
            uint4 kv_ = *(const uint4*)&qkv[rb + 1024 + u * 8];
            uint4 vv = *(const uint4*)&qkv[rb + 2048 + u * 8];
            const unsigned* qa = (const unsigned*)&qv;
            const unsigned* ka = (const unsigned*)&kv_;
            const unsigned* va = (const unsigned*)&vv;
#pragma unroll
            for (int t2 = 0; t2 < 4; t2++) {
                const int dd = gq * 16 + u * 8 + t2 * 2;
                qs[c * LDP + dd]     = bf2f((u16)(qa[t2] & 0xFFFF));
                qs[c * LDP + dd + 1] = bf2f((u16)(qa[t2] >> 16));
                ks[c * LDP + dd]     = bf2f((u16)(ka[t2] & 0xFFFF));
                ks[c * LDP + dd + 1] = bf2f((u16)(ka[t2] >> 16));
                vs[c * LDP + dd]     = bf2f((u16)(va[t2] & 0xFFFF));
                vs[c * LDP + dd + 1] = bf2f((u16)(va[t2] >> 16));
            }
        }
        const size_t gb = (size_t)(tok0 + c) * 1024 + h * 64 + gq * 16;
#pragma unroll
        for (int u = 0; u < 4; u++) {
            float4 gv = *(const float4*)&g[gb + u * 4];
            const float* ga = (const float*)&gv;
#pragma unroll
            for (int t2 = 0; t2 < 4; t2++) {
                const int dd = gq * 16 + u * 4 + t2;
                const float z = ga[t2] + bg[h * 64 + dd];
                const float al = 1.f / (1.f + __expf(-z));
                la[c * LDP + dd] = __logf(fmaxf(al, 1e-6f));
            }
        }
    }
    __syncthreads();
    if (tid < 64) {                 // cumsum along chunk position, per d
        const int d = tid;
        float run = 0.f;
        for (int cc = 0; cc < 64; cc++) { run += la[cc * LDP + d]; la[cc * LDP + d] = run; }
    }
    __syncthreads();
    if (tid < 64) {                 // row stats: la_mean, 1/||q||, 1/||k||; chunk decay
        const int cc = tid;
        float s = 0.f, sq = 0.f, sk = 0.f;
        for (int j = 0; j < 64; j++) {
            s += la[cc * LDP + j];
            const float qv = qs[cc * LDP + j]; sq += qv * qv;
            const float kv_ = ks[cc * LDP + j]; sk += kv_ * kv_;
        }
        lm[cc] = s * (1.f / 64.f);
        nqi[cc] = 1.f / fmaxf(sqrtf(sq), 1e-12f);
        nki[cc] = 1.f / fmaxf(sqrtf(sk), 1e-12f);
        cdec[((size_t)bh * 64 + ck) * 64 + tid] = __expf(la[63 * LDP + tid]);
    }
    __syncthreads();
    {   // intra-chunk attention + o_intra. 4-thread group per row c; e in [gq*16,+16)
        float qreg[16];
#pragma unroll
        for (int i = 0; i < 16; i++) qreg[i] = qs[c * LDP + gq * 16 + i];
        float accv[16];
#pragma unroll
        for (int e = 0; e < 16; e++) accv[e] = 0.f;
        const float qn = nqi[c], lmc = lm[c];
        for (int m = 0; m <= c; m++) {
            float p = 0.f;
#pragma unroll
            for (int i = 0; i < 16; i++) p += qreg[i] * ks[m * LDP + gq * 16 + i];
            p += __shfl_xor(p, 1);
            p += __shfl_xor(p, 2);
            const float wgt = p * qn * nki[m] * __expf(lmc - lm[m]);
            const float* vrow = &vs[m * LDP + gq * 16];
#pragma unroll
            for (int e = 0; e < 16; e++) accv[e] += wgt * vrow[e];
        }
        float* orow = &ointra[((size_t)bh * 4096 + ck * 64 + c) * 64 + gq * 16];
#pragma unroll
        for (int e = 0; e < 16; e++) orow[e] = accv[e];
    }
    {   // q_dec = q_hat * exp(la_cum)  -> bf16
        const float qn = nqi[c];
        u16* qrow = &qdec[((size_t)bh * 4096 + ck * 64 + c) * 64 + gq * 16];
#pragma unroll
        for (int i = 0; i < 16; i++) {
            const int dd = gq * 16 + i;
            qrow[i] = f2bf(qs[c * LDP + dd] * qn * __expf(la[c * LDP + dd]));
        }
    }
    {   // kv_chunk[f][e] = sum_c k_hat[c,f]*exp(la_end[f]-la_cum[c,f]) * v[c,e]
        const int f = c;
        float accv[16];
#pragma unroll
        for (int e = 0; e < 16; e++) accv[e] = 0.f;
        const float laend = la[63 * LDP + f];
        for (int cc = 0; cc < 64; cc++) {
            const float wgt = ks[cc * LDP + f] * nki[cc] * __expf(laend - la[cc * LDP + f]);
            const float* vrow = &vs[cc * LDP + gq * 16];
#pragma unroll
            for (int e = 0; e < 16; e++) accv[e] += wgt * vrow[e];
        }
        float* kvrow = &kvout[(((size_t)bh * 64 + ck) * 64 + f) * 64 + gq * 16];
#pragma unroll
        for (int e = 0; e < 16; e++) kvrow[e] = accv[e];
    }
}

// ---------------------------------------------------------------- elementwise chunk scan
__global__ __launch_bounds__(256) void gla_scan(
    const float* __restrict__ kv, const float* __restrict__ cdec,
    float* __restrict__ Sprev)
{
    const int bh = blockIdx.x >> 4;
    const int de = (blockIdx.x & 15) * 256 + threadIdx.x;   // (d,e) pair
    const int d = de >> 6;
    float s = 0.f;
    const size_t base = (size_t)bh * 64 * 4096 + de;
    const size_t cb = (size_t)bh * 64 * 64 + d;
    for (int t = 0; t < 64; t++) {
        Sprev[base + (size_t)t * 4096] = s;
        s = s * cdec[cb + (size_t)t * 64] + kv[base + (size_t)t * 4096];
    }
}

// ---------------------------------------------------------------- o_inter + combine -> bf16
__global__ __launch_bounds__(256) void gla_b(
    const u16* __restrict__ qdec, const float* __restrict__ Sprev,
    const float* __restrict__ ointra, u16* __restrict__ obf)
{
    __shared__ float Ss[64 * LDP];
    __shared__ float qd[64 * LDP];
    const int bid = blockIdx.x;
    const int bh = bid >> 6, ck = bid & 63;
    const int b = bh >> 4, h = bh & 15;
    const int tid = threadIdx.x;
    const int c = tid >> 2, gq = tid & 3;
    {
        const size_t sb = (((size_t)bh * 64 + ck) * 64 + c) * 64 + gq * 16;
#pragma unroll
        for (int u = 0; u < 4; u++) {
            float4 sv = *(const float4*)&Sprev[sb + u * 4];
            Ss[c * LDP + gq * 16 + u * 4 + 0] = sv.x;
            Ss[c * LDP + gq * 16 + u * 4 + 1] = sv.y;
            Ss[c * LDP + gq * 16 + u * 4 + 2] = sv.z;
            Ss[c * LDP + gq * 16 + u * 4 + 3] = sv.w;
        }
        const size_t qb = ((size_t)bh * 4096 + ck * 64 + c) * 64 + gq * 16;
#pragma unroll
        for (int u = 0; u < 2; u++) {
            uint4 qv = *(const uint4*)&qdec[qb + u * 8];
            const unsigned* qa = (const unsigned*)&qv;
#pragma unroll
            for (int t2 = 0; t2 < 4; t2++) {
                const int dd = gq * 16 + u * 8 + t2 * 2;
                qd[c * LDP + dd]     = bf2f((u16)(qa[t2] & 0xFFFF));
                qd[c * LDP + dd + 1] = bf2f((u16)(qa[t2] >> 16));
            }
        }
    }
    __syncthreads();
    float accv[16];
    const float* orow = &ointra[((size_t)bh * 4096 + ck * 64 + c) * 64 + gq * 16];
#pragma unroll
    for (int e = 0; e < 16; e++) accv[e] = orow[e];
    for (int d0 = 0; d0 < 64; d0++) {
        const float qv = qd[c * LDP + d0];
        const float* srow = &Ss[d0 * LDP + gq * 16];
#pragma unroll
        for (int e = 0; e < 16; e++) accv[e] += qv * srow[e];
    }
    const int tok = b * 4096 + ck * 64 + c;
    u16* out = &obf[(size_t)tok * 1024 + h * 64 + gq * 16];
    unsigned ow[8];
#pragma unroll
    for (int t2 = 0; t2 < 8; t2++)
        ow[t2] = (unsigned)f2bf(accv[t2 * 2]) | ((unsigned)f2bf(accv[t2 * 2 + 1]) << 16);
    *(uint4*)&out[0] = *(const uint4*)&ow[0];
    *(uint4*)&out[8] = *(const uint4*)&ow[4];
}

__global__ void fill_sentinel(float* out, int n) {
    int i = blockIdx.x * 256 + threadIdx.x;
    if (i < n) out[i] = 12345.0f;
}

// ---------------------------------------------------------------- host launcher
extern "C" void kernel_launch(void* const* d_in, const int* in_sizes, int n_in,
                              void* d_out, int out_size, void* d_ws, size_t ws_size,
                              hipStream_t stream)
{
    const float* x    = (const float*)d_in[0];
    const float* Wq   = (const float*)d_in[1];
    const float* Wk   = (const float*)d_in[2];
    const float* Wv   = (const float*)d_in[3];
    const float* Wg   = (const float*)d_in[4];
    const float* bg   = (const float*)d_in[5];
    const float* Wo   = (const float*)d_in[6];
    const float* ln1w = (const float*)d_in[7];
    const float* ln1b = (const float*)d_in[8];
    const float* ln2w = (const float*)d_in[9];
    const float* ln2b = (const float*)d_in[10];
    const float* W1   = (const float*)d_in[11];
    const float* b1   = (const float*)d_in[12];
    const float* W2   = (const float*)d_in[13];
    const float* b2   = (const float*)d_in[14];
    float* out = (float*)d_out;

    char* ws = (char*)d_ws;
    // layout (bytes)
    u16*   wtQKVG = (u16*)(ws + 0);            // 4096x1024 bf16  (Wq|Wk|Wv|Wg cols, transposed)
    u16*   wtWo   = (u16*)(ws + 8388608);      // 1024x1024
    u16*   wtW1   = (u16*)(ws + 10485760);     // 4096x1024
    u16*   wtW2   = (u16*)(ws + 18874368);     // 1024x4096
    u16*   xnb    = (u16*)(ws + 27262976);     // 8192x1024 bf16
    u16*   qkvb   = (u16*)(ws + 44040192);     // 8192x3072 bf16
    float* gbuf   = (float*)(ws + 94371840);   // 8192x1024 f32
    float* kvbuf  = (float*)(ws + 127926272);  // 32x64x64x64 f32
    float* cdbuf  = (float*)(ws + 161480704);  // 32x64x64 f32
    u16*   qdecb  = (u16*)(ws + 162004992);    // 32x4096x64 bf16
    float* ointra = (float*)(ws + 178782208);  // 32x4096x64 f32
    u16*   obf    = (u16*)(ws + 212336640);    // 8192x1024 bf16
    u16*   hbf    = (u16*)(ws + 229113856);    // 8192x1024 bf16
    // reuse (stream-ordered, regions dead by then)
    float* sprev  = (float*)(ws + 94371840);   // over gbuf
    float* x2     = (float*)(ws + 178782208);  // over ointra
    u16*   ffnb   = (u16*)(ws + 27262976);     // over xnb+qkvb (8192x4096 bf16)

    if (ws_size < 245891072u) {
        fill_sentinel<<<dim3((out_size + 255) / 256), dim3(256), 0, stream>>>(out, out_size);
        return;
    }

    const dim3 b256(256), b32x8(32, 8);

    // weight transpose+convert
    transpose_bf16<<<dim3(32, 32),  b32x8, 0, stream>>>(Wq, wtQKVG,                 1024, 1024);
    transpose_bf16<<<dim3(32, 32),  b32x8, 0, stream>>>(Wk, wtQKVG + 1024 * 1024,   1024, 1024);
    transpose_bf16<<<dim3(32, 32),  b32x8, 0, stream>>>(Wv, wtQKVG + 2048 * 1024,   1024, 1024);
    transpose_bf16<<<dim3(32, 32),  b32x8, 0, stream>>>(Wg, wtQKVG + 3072 * 1024,   1024, 1024);
    transpose_bf16<<<dim3(32, 32),  b32x8, 0, stream>>>(Wo, wtWo,                   1024, 1024);
    transpose_bf16<<<dim3(32, 128), b32x8, 0, stream>>>(W1, wtW1,                   1024, 4096);
    transpose_bf16<<<dim3(128, 32), b32x8, 0, stream>>>(W2, wtW2,                   4096, 1024);

    // LN1
    ln_bf16<<<dim3(8192), b256, 0, stream>>>(x, ln1w, ln1b, xnb);
    // q,k,v (bf16 out) and gate logits (f32 out)
    gemm_bt<1><<<dim3(64, 24), b256, 0, stream>>>(xnb, wtQKVG, nullptr, qkvb, nullptr, nullptr, 8192, 3072, 1024);
    gemm_bt<0><<<dim3(64, 8),  b256, 0, stream>>>(xnb, wtQKVG + 3072 * 1024, gbuf, nullptr, nullptr, nullptr, 8192, 1024, 1024);
    // GLA
    gla_a<<<dim3(2048), b256, 0, stream>>>(qkvb, gbuf, bg, qdecb, kvbuf, cdbuf, ointra);
    gla_scan<<<dim3(512), b256, 0, stream>>>(kvbuf, cdbuf, sprev);
    gla_b<<<dim3(2048), b256, 0, stream>>>(qdecb, sprev, ointra, obf);
    // output proj + residual
    gemm_bt<2><<<dim3(64, 8), b256, 0, stream>>>(obf, wtWo, x2, nullptr, nullptr, x, 8192, 1024, 1024);
    // LN2 + FFN
    ln_bf16<<<dim3(8192), b256, 0, stream>>>(x2, ln2w, ln2b, hbf);
    gemm_bt<3><<<dim3(64, 32), b256, 0, stream>>>(hbf, wtW1, nullptr, ffnb, b1, nullptr, 8192, 4096, 1024);
    gemm_bt<4><<<dim3(64, 8),  b256, 0, stream>>>(ffnb, wtW2, out, nullptr, b2, x2, 8192, 1024, 4096);
}

// Round 2
// 422.972 us; speedup vs baseline: 1.4252x; 1.4252x over previous
//
#include <hip/hip_runtime.h>

#define AS1 __attribute__((address_space(1)))
#define AS3 __attribute__((address_space(3)))

typedef unsigned short u16;
typedef short s16x8 __attribute__((ext_vector_type(8)));
typedef float f32x4 __attribute__((ext_vector_type(4)));

__device__ __forceinline__ float bf2f(u16 u) {
    union { unsigned u; float f; } v; v.u = ((unsigned)u) << 16; return v.f;
}
__device__ __forceinline__ u16 f2bf(float f) {
    union { float f; unsigned u; } v; v.f = f;
    unsigned u = v.u;
    return (u16)((u + 0x7FFFu + ((u >> 16) & 1u)) >> 16);
}

__device__ __forceinline__ void gload16(const void* g, void* l) {
    __builtin_amdgcn_global_load_lds((const AS1 void*)g, (AS3 void*)l, 16, 0, 0);
}

// ---------------------------------------------------------------- transpose+cvt
__global__ __launch_bounds__(256) void transpose_bf16(
    const float* __restrict__ src, u16* __restrict__ dst, int R, int C)
{
    __shared__ float t[32][33];
    const int tx = threadIdx.x, ty = threadIdx.y;
    const int r0 = blockIdx.x * 32, c0 = blockIdx.y * 32;
#pragma unroll
    for (int i = 0; i < 4; i++)
        t[ty + i * 8][tx] = src[(size_t)(r0 + ty + i * 8) * C + c0 + tx];
    __syncthreads();
#pragma unroll
    for (int i = 0; i < 4; i++)
        dst[(size_t)(c0 + ty + i * 8) * R + r0 + tx] = f2bf(t[tx][ty + i * 8]);
}

// ---------------------------------------------------------------- layernorm -> bf16
__global__ __launch_bounds__(256) void ln_bf16(
    const float* __restrict__ x, const float* __restrict__ w,
    const float* __restrict__ b, u16* __restrict__ out)
{
    __shared__ float red[8];
    const int row = blockIdx.x;
    const int tid = threadIdx.x;
    const size_t base = (size_t)row * 1024 + tid * 4;
    const float4 xv = *(const float4*)&x[base];
    float s = xv.x + xv.y + xv.z + xv.w;
    float q = xv.x * xv.x + xv.y * xv.y + xv.z * xv.z + xv.w * xv.w;
#pragma unroll
    for (int m = 1; m < 64; m <<= 1) { s += __shfl_xor(s, m); q += __shfl_xor(q, m); }
    if ((tid & 63) == 0) { red[tid >> 6] = s; red[4 + (tid >> 6)] = q; }
    __syncthreads();
    s = red[0] + red[1] + red[2] + red[3];
    q = red[4] + red[5] + red[6] + red[7];
    const float mu = s * (1.f / 1024.f);
    const float var = q * (1.f / 1024.f) - mu * mu;
    const float rs = rsqrtf(var + 1e-5f);
    const float4 wv = *(const float4*)&w[tid * 4];
    const float4 bv = *(const float4*)&b[tid * 4];
    uint2 ov;
    ov.x = (unsigned)f2bf((xv.x - mu) * rs * wv.x + bv.x) |
           ((unsigned)f2bf((xv.y - mu) * rs * wv.y + bv.y) << 16);
    ov.y = (unsigned)f2bf((xv.z - mu) * rs * wv.z + bv.z) |
           ((unsigned)f2bf((xv.w - mu) * rs * wv.w + bv.w) << 16);
    *(uint2*)&out[base] = ov;
}

// ---------------------------------------------------------------- bf16 MFMA GEMM, B^T
// EP: 0 = f32; 1 = bf16; 2 = f32 +resid; 3 = bf16 gelu(acc+bias); 4 = f32 +bias+resid
template <int EP>
__global__ __launch_bounds__(256, 2) void gemm_bt(
    const u16* __restrict__ A, const u16* __restrict__ BT,
    float* __restrict__ Cf, u16* __restrict__ Cb,
    const float* __restrict__ bias, const float* __restrict__ resid,
    int M, int N, int K)
{
    __shared__ u16 As[4096];
    __shared__ u16 Bs[4096];
    const int tid = threadIdx.x;
    const int w = tid >> 6;
    const int l = tid & 63;
    const int tm = blockIdx.x * 128;
    const int tn = blockIdx.y * 128;
    const int wm = (w >> 1) * 64;
    const int wn = (w & 1) * 64;

    f32x4 acc[4][4] = {};

    const int e0 = w * 512 + l * 8;
    const int r0 = e0 >> 5, c0 = e0 & 31;
    const int e1 = 2048 + e0;
    const int r1 = e1 >> 5, c1 = e1 & 31;
    const size_t arow0 = (size_t)(tm + r0) * K + c0;
    const size_t arow1 = (size_t)(tm + r1) * K + c1;
    const size_t brow0 = (size_t)(tn + r0) * K + c0;
    const size_t brow1 = (size_t)(tn + r1) * K + c1;
    const int lofs = w * 512;
    const int afr = wm + (l & 15);
    const int bfr = wn + (l & 15);
    const int kk = (l >> 4) * 8;

    for (int k0 = 0; k0 < K; k0 += 32) {
        gload16(&A[arow0 + k0], &As[lofs]);
        gload16(&A[arow1 + k0], &As[2048 + lofs]);
        gload16(&BT[brow0 + k0], &Bs[lofs]);
        gload16(&BT[brow1 + k0], &Bs[2048 + lofs]);
        __syncthreads();
        s16x8 a[4], b[4];
#pragma unroll
        for (int i = 0; i < 4; i++) a[i] = *(const s16x8*)&As[(afr + i * 16) * 32 + kk];
#pragma unroll
        for (int j = 0; j < 4; j++) b[j] = *(const s16x8*)&Bs[(bfr + j * 16) * 32 + kk];
#pragma unroll
        for (int i = 0; i < 4; i++)
#pragma unroll
            for (int j = 0; j < 4; j++)
                acc[i][j] = __builtin_amdgcn_mfma_f32_16x16x32_bf16(a[i], b[j], acc[i][j], 0, 0, 0);
        __syncthreads();
    }

    const int erow = tm + wm + (l >> 4) * 4;
    const int ecol = tn + wn + (l & 15);
#pragma unroll
    for (int i = 0; i < 4; i++) {
#pragma unroll
        for (int j = 0; j < 4; j++) {
            const int col = ecol + j * 16;
#pragma unroll
            for (int r = 0; r < 4; r++) {
                const int row = erow + i * 16 + r;
                const size_t idx = (size_t)row * N + col;
                const float v = acc[i][j][r];
                if (EP == 0) {
                    Cf[idx] = v;
                } else if (EP == 1) {
                    Cb[idx] = f2bf(v);
                } else if (EP == 2) {
                    Cf[idx] = v + resid[idx];
                } else if (EP == 3) {
                    const float u = v + bias[col];
                    Cb[idx] = f2bf(0.5f * u * (1.f + erff(u * 0.70710678118654752f)));
                } else {
                    Cf[idx] = v + bias[col] + resid[idx];
                }
            }
        }
    }
}

// ---------------------------------------------------------------- GLA phase A (MFMA)
// One block per (bh, chunk). 4 waves; wave w owns output rows w*16..w*16+15.
#define TP 72   // u16 row stride for bf16 64x64 tiles (144B -> 2-way max)
#define LP 65   // f32 row stride for log-alpha tile
__global__ __launch_bounds__(256) void gla_a(
    const u16* __restrict__ qkv,     // (8192,3072) bf16: q|k|v col-blocks of 1024
    const float* __restrict__ g,     // (8192,1024) f32 gate logits (pre-bias)
    const float* __restrict__ bg,    // (1024)
    u16* __restrict__ qdec,          // [bh][4096][64] bf16
    u16* __restrict__ kvT,           // [bh][64][64(e)][64(f)] bf16  (transposed kv)
    float* __restrict__ cdec,        // [bh][64][64] f32
    u16* __restrict__ ointra)        // [bh][4096][64] bf16
{
    __shared__ u16 Qh[64 * TP];      // q_hat; reused as attn tile
    __shared__ u16 Kh[64 * TP];      // k_hat
    __shared__ u16 VT[64 * TP];      // V transposed (rows = e)
    __shared__ float L[64 * LP];     // la_cum; reused (as u16) for KDT (rows = f)
    __shared__ float lm[64], nq[64], nk[64];

    const int bid = blockIdx.x;
    const int bh = bid >> 6, ck = bid & 63;
    const int b = bh >> 4, h = bh & 15;
    const int tok0 = b * 4096 + ck * 64;
    const int tid = threadIdx.x;
    const int w = tid >> 6, l = tid & 63;

    // ---- phase 1: load q,k,v bf16; build VT; compute log-alpha -> L
#pragma unroll
    for (int pass = 0; pass < 2; pass++) {
        const int c = (tid >> 3) + pass * 32;
        const int col = (tid & 7) * 8;
        const size_t rb = (size_t)(tok0 + c) * 3072 + h * 64 + col;
        uint4 qv = *(const uint4*)&qkv[rb];
        uint4 kv_ = *(const uint4*)&qkv[rb + 1024];
        uint4 vv = *(const uint4*)&qkv[rb + 2048];
        *(uint4*)&Qh[c * TP + col] = qv;
        *(uint4*)&Kh[c * TP + col] = kv_;
        const u16* va = (const u16*)&vv;
#pragma unroll
        for (int j = 0; j < 8; j++) VT[(col + j) * TP + c] = va[j];
    }
#pragma unroll
    for (int pass = 0; pass < 4; pass++) {
        const int c = (tid >> 4) + pass * 16;
        const int col = (tid & 15) * 4;
        float4 gv = *(const float4*)&g[(size_t)(tok0 + c) * 1024 + h * 64 + col];
        float4 bgv = *(const float4*)&bg[h * 64 + col];
        const float* ga = (const float*)&gv;
        const float* ba = (const float*)&bgv;
#pragma unroll
        for (int i = 0; i < 4; i++) {
            const float z = ga[i] + ba[i];
            const float al = 1.f / (1.f + __expf(-z));
            L[c * LP + col + i] = __logf(fmaxf(al, 1e-6f));
        }
    }
    __syncthreads();

    // ---- phase 2: cumsum over c (per d). thread (d = tid>>2, qq = tid&3) owns 16 rows.
    {
        const int d = tid >> 2, qq = tid & 3;
        float vals[16];
#pragma unroll
        for (int i = 0; i < 16; i++) vals[i] = L[(qq * 16 + i) * LP + d];
        float s = 0.f;
#pragma unroll
        for (int i = 0; i < 16; i++) { s += vals[i]; vals[i] = s; }
        float sum = s;
        float u1 = __shfl_up(sum, 1, 4); if (qq >= 1) sum += u1;
        float u2 = __shfl_up(sum, 2, 4); if (qq >= 2) sum += u2;
        const float excl = sum - s;
#pragma unroll
        for (int i = 0; i < 16; i++) L[(qq * 16 + i) * LP + d] = vals[i] + excl;
        if (qq == 3) cdec[((size_t)bh * 64 + ck) * 64 + d] = __expf(sum);
    }
    __syncthreads();

    // ---- phase 3: row stats: lm (mean la_cum), 1/||q||, 1/||k||
    {
        const int c = tid >> 2, qq = tid & 3;
        float sl = 0.f, sq = 0.f, sk = 0.f;
        uint4 qa = *(const uint4*)&Qh[c * TP + qq * 16];
        uint4 qb = *(const uint4*)&Qh[c * TP + qq * 16 + 8];
        uint4 ka = *(const uint4*)&Kh[c * TP + qq * 16];
        uint4 kb = *(const uint4*)&Kh[c * TP + qq * 16 + 8];
        const u16* qu = (const u16*)&qa; const u16* qu2 = (const u16*)&qb;
        const u16* ku = (const u16*)&ka; const u16* ku2 = (const u16*)&kb;
#pragma unroll
        for (int i = 0; i < 8; i++) {
            float q1 = bf2f(qu[i]), q2 = bf2f(qu2[i]);
            float k1 = bf2f(ku[i]), k2 = bf2f(ku2[i]);
            sq += q1 * q1 + q2 * q2;
            sk += k1 * k1 + k2 * k2;
        }
#pragma unroll
        for (int i = 0; i < 16; i++) sl += L[c * LP + qq * 16 + i];
        sl += __shfl_xor(sl, 1); sl += __shfl_xor(sl, 2);
        sq += __shfl_xor(sq, 1); sq += __shfl_xor(sq, 2);
        sk += __shfl_xor(sk, 1); sk += __shfl_xor(sk, 2);
        if (qq == 0) {
            lm[c] = sl * (1.f / 64.f);
            nq[c] = 1.f / fmaxf(sqrtf(sq), 1e-12f);
            nk[c] = 1.f / fmaxf(sqrtf(sk), 1e-12f);
        }
    }
    __syncthreads();

    // ---- phase 4: normalize Qh,Kh in place; write qdec; compute KDT values into regs
    u16 kdt[16];
    {
        const int c = tid >> 2, qq = tid & 3;
        const float qn = nq[c], kn = nk[c];
        uint4 qa = *(const uint4*)&Qh[c * TP + qq * 16];
        uint4 qb = *(const uint4*)&Qh[c * TP + qq * 16 + 8];
        uint4 ka = *(const uint4*)&Kh[c * TP + qq * 16];
        uint4 kb = *(const uint4*)&Kh[c * TP + qq * 16 + 8];
        u16* qu = (u16*)&qa; u16* qu2 = (u16*)&qb;
        u16* ku = (u16*)&ka; u16* ku2 = (u16*)&kb;
        float Lc[16], Le[16];
#pragma unroll
        for (int i = 0; i < 16; i++) {
            Lc[i] = L[c * LP + qq * 16 + i];
            Le[i] = L[63 * LP + qq * 16 + i];
        }
        unsigned qd[8];
#pragma unroll
        for (int i = 0; i < 8; i++) {
            float qh1 = bf2f(qu[i]) * qn;  qu[i] = f2bf(qh1);
            float qh2 = bf2f(qu2[i]) * qn; qu2[i] = f2bf(qh2);
            float kh1 = bf2f(ku[i]) * kn;  ku[i] = f2bf(kh1);
            float kh2 = bf2f(ku2[i]) * kn; ku2[i] = f2bf(kh2);
            kdt[i]     = f2bf(kh1 * __expf(Le[i] - Lc[i]));
            kdt[i + 8] = f2bf(kh2 * __expf(Le[i + 8] - Lc[i + 8]));
            const unsigned lo = (unsigned)f2bf(qh1 * __expf(Lc[i]));
            const unsigned hi = (i < 4) ? 0u : 0u;  // placeholder, filled below
            qd[i] = lo; (void)hi;
        }
        // pack qdec pairs: elements i and i+? -> build from scalars
        unsigned pk[8];
#pragma unroll
        for (int i = 0; i < 4; i++) {
            pk[i]     = qd[2 * i] | (qd[2 * i + 1] << 16);
        }
#pragma unroll
        for (int i = 0; i < 4; i++) {
            const float qh1 = bf2f(qu2[2 * i]) * 1.f;   // already normalized above
            const float qh2 = bf2f(qu2[2 * i + 1]) * 1.f;
            pk[4 + i] = (unsigned)f2bf(qh1 * __expf(Lc[8 + 2 * i])) |
                        ((unsigned)f2bf(qh2 * __expf(Lc[8 + 2 * i + 1])) << 16);
        }
        *(uint4*)&Qh[c * TP + qq * 16] = qa;
        *(uint4*)&Qh[c * TP + qq * 16 + 8] = qb;
        *(uint4*)&Kh[c * TP + qq * 16] = ka;
        *(uint4*)&Kh[c * TP + qq * 16 + 8] = kb;
        u16* qrow = &qdec[((size_t)bh * 4096 + ck * 64 + c) * 64 + qq * 16];
        *(uint4*)&qrow[0] = *(const uint4*)&pk[0];
        *(uint4*)&qrow[8] = *(const uint4*)&pk[4];
    }
    __syncthreads();

    // ---- phase 5: write KDT (rows = f) into L-space; S1 = Qh x Kh^T MFMA
    u16* KDT = (u16*)L;
    {
        const int c = tid >> 2, qq = tid & 3;
#pragma unroll
        for (int i = 0; i < 16; i++) KDT[(qq * 16 + i) * TP + c] = kdt[i];
    }
    const int fr = l & 15;
    const int kk = (l >> 4) * 8;
    f32x4 accS[4] = {};
#pragma unroll
    for (int ks = 0; ks < 2; ks++) {
        s16x8 af = *(const s16x8*)&Qh[(w * 16 + fr) * TP + ks * 32 + kk];
#pragma unroll
        for (int j = 0; j < 4; j++) {
            s16x8 bf = *(const s16x8*)&Kh[(j * 16 + fr) * TP + ks * 32 + kk];
            accS[j] = __builtin_amdgcn_mfma_f32_16x16x32_bf16(af, bf, accS[j], 0, 0, 0);
        }
    }
    __syncthreads();   // S1 reads of Qh done; KDT written

    // ---- phase 6: attn = S1 * decay * tril -> bf16 into Qh-space
    {
        const int erow = w * 16 + (l >> 4) * 4;
#pragma unroll
        for (int j = 0; j < 4; j++) {
            const int mm = j * 16 + (l & 15);
            const float lmm = lm[mm];
#pragma unroll
            for (int r = 0; r < 4; r++) {
                const int cc = erow + r;
                const float wgt = (mm <= cc) ? __expf(lm[cc] - lmm) : 0.f;
                Qh[cc * TP + mm] = f2bf(accS[j][r] * wgt);
            }
        }
    }
    __syncthreads();

    // ---- phase 7: o_intra = attn x V  (B = VT rows e); kv^T = V^T x KD (A = VT rows e)
    f32x4 accO[4] = {};
    f32x4 accK[4] = {};
#pragma unroll
    for (int ks = 0; ks < 2; ks++) {
        s16x8 aAt = *(const s16x8*)&Qh[(w * 16 + fr) * TP + ks * 32 + kk];
        s16x8 aVt = *(const s16x8*)&VT[(w * 16 + fr) * TP + ks * 32 + kk];
#pragma unroll
        for (int j = 0; j < 4; j++) {
            s16x8 bVt = *(const s16x8*)&VT[(j * 16 + fr) * TP + ks * 32 + kk];
            s16x8 bKd = *(const s16x8*)&KDT[(j * 16 + fr) * TP + ks * 32 + kk];
            accO[j] = __builtin_amdgcn_mfma_f32_16x16x32_bf16(aAt, bVt, accO[j], 0, 0, 0);
            accK[j] = __builtin_amdgcn_mfma_f32_16x16x32_bf16(aVt, bKd, accK[j], 0, 0, 0);
        }
    }
    {
        const int erow = w * 16 + (l >> 4) * 4;
#pragma unroll
        for (int j = 0; j < 4; j++) {
            const int col = j * 16 + (l & 15);
#pragma unroll
            for (int r = 0; r < 4; r++) {
                const int row = erow + r;
                ointra[((size_t)bh * 4096 + ck * 64 + row) * 64 + col] = f2bf(accO[j][r]);
                kvT[(((size_t)bh * 64 + ck) * 64 + row) * 64 + col] = f2bf(accK[j][r]);
            }
        }
    }
}

// ---------------------------------------------------------------- elementwise chunk scan
__global__ __launch_bounds__(256) void gla_scan(
    const u16* __restrict__ kvT, const float* __restrict__ cdec,
    u16* __restrict__ ST)       // [bh][64][64(e)][64(d)] bf16, state BEFORE chunk
{
    const int bh = blockIdx.x >> 4;
    const int de = (blockIdx.x & 15) * 256 + threadIdx.x;  // e = de>>6, d = de&63
    const int d = de & 63;
    float s = 0.f;
    const size_t base = (size_t)bh * 64 * 4096 + de;
    const size_t cb = (size_t)bh * 4096 + d;
    for (int t = 0; t < 64; t++) {
        ST[base + (size_t)t * 4096] = f2bf(s);
        s = s * cdec[cb + (size_t)t * 64] + bf2f(kvT[base + (size_t)t * 4096]);
    }
}

// ---------------------------------------------------------------- GLA phase B (MFMA)
__global__ __launch_bounds__(256) void gla_b(
    const u16* __restrict__ qdec, const u16* __restrict__ ST,
    const u16* __restrict__ ointra, u16* __restrict__ obf)
{
    __shared__ u16 Qd[64 * TP];
    __shared__ u16 Sd[64 * TP];
    const int bid = blockIdx.x;
    const int bh = bid >> 6, ck = bid & 63;
    const int b = bh >> 4, h = bh & 15;
    const int tid = threadIdx.x;
    const int w = tid >> 6, l = tid & 63;
#pragma unroll
    for (int pass = 0; pass < 2; pass++) {
        const int r = (tid >> 3) + pass * 32;
        const int col = (tid & 7) * 8;
        *(uint4*)&Qd[r * TP + col] =
            *(const uint4*)&qdec[((size_t)bh * 4096 + ck * 64 + r) * 64 + col];
        *(uint4*)&Sd[r * TP + col] =
            *(const uint4*)&ST[(((size_t)bh * 64 + ck) * 64 + r) * 64 + col];
    }
    __syncthreads();
    const int fr = l & 15;
    const int kk = (l >> 4) * 8;
    f32x4 acc[4] = {};
#pragma unroll
    for (int ks = 0; ks < 2; ks++) {
        s16x8 af = *(const s16x8*)&Qd[(w * 16 + fr) * TP + ks * 32 + kk];
#pragma unroll
        for (int j = 0; j < 4; j++) {
            s16x8 bf = *(const s16x8*)&Sd[(j * 16 + fr) * TP + ks * 32 + kk];
            acc[j] = __builtin_amdgcn_mfma_f32_16x16x32_bf16(af, bf, acc[j], 0, 0, 0);
        }
    }
    const int erow = w * 16 + (l >> 4) * 4;
#pragma unroll
    for (int j = 0; j < 4; j++) {
        const int e = j * 16 + (l & 15);
#pragma unroll
        for (int r = 0; r < 4; r++) {
            const int cc = erow + r;
            const size_t ia = ((size_t)bh * 4096 + ck * 64 + cc) * 64 + e;
            const float v = acc[j][r] + bf2f(ointra[ia]);
            obf[(size_t)(b * 4096 + ck * 64 + cc) * 1024 + h * 64 + e] = f2bf(v);
        }
    }
}

__global__ void fill_sentinel(float* out, int n) {
    int i = blockIdx.x * 256 + threadIdx.x;
    if (i < n) out[i] = 12345.0f;
}

// ---------------------------------------------------------------- host launcher
extern "C" void kernel_launch(void* const* d_in, const int* in_sizes, int n_in,
                              void* d_out, int out_size, void* d_ws, size_t ws_size,
                              hipStream_t stream)
{
    const float* x    = (const float*)d_in[0];
    const float* Wq   = (const float*)d_in[1];
    const float* Wk   = (const float*)d_in[2];
    const float* Wv   = (const float*)d_in[3];
    const float* Wg   = (const float*)d_in[4];
    const float* bg   = (const float*)d_in[5];
    const float* Wo   = (const float*)d_in[6];
    const float* ln1w = (const float*)d_in[7];
    const float* ln1b = (const float*)d_in[8];
    const float* ln2w = (const float*)d_in[9];
    const float* ln2b = (const float*)d_in[10];
    const float* W1   = (const float*)d_in[11];
    const float* b1   = (const float*)d_in[12];
    const float* W2   = (const float*)d_in[13];
    const float* b2   = (const float*)d_in[14];
    float* out = (float*)d_out;

    char* ws = (char*)d_ws;
    u16*   wtQKVG = (u16*)(ws + 0);            // 4096x1024 bf16
    u16*   wtWo   = (u16*)(ws + 8388608);      // 1024x1024
    u16*   wtW1   = (u16*)(ws + 10485760);     // 4096x1024
    u16*   wtW2   = (u16*)(ws + 18874368);     // 1024x4096
    u16*   xnb    = (u16*)(ws + 27262976);     // 8192x1024 bf16
    u16*   qkvb   = (u16*)(ws + 44040192);     // 8192x3072 bf16
    float* gbuf   = (float*)(ws + 94371840);   // 8192x1024 f32
    u16*   kvT    = (u16*)(ws + 127926272);    // 32x64x64x64 bf16
    float* cdbuf  = (float*)(ws + 144703488);  // 32x64x64 f32
    u16*   qdecb  = (u16*)(ws + 145227776);    // 32x4096x64 bf16
    u16*   ointra = (u16*)(ws + 162004992);    // 32x4096x64 bf16
    u16*   STb    = (u16*)(ws + 178782208);    // 32x64x64x64 bf16
    u16*   obf    = (u16*)(ws + 195559424);    // 8192x1024 bf16
    u16*   hbf    = (u16*)(ws + 212336640);    // 8192x1024 bf16
    // stream-ordered reuse
    float* x2     = (float*)(ws + 94371840);   // over gbuf (dead after gla_a)
    u16*   ffnb   = (u16*)(ws + 27262976);     // over xnb+qkvb (dead after gla_a)

    if (ws_size < 229113856u) {
        fill_sentinel<<<dim3((out_size + 255) / 256), dim3(256), 0, stream>>>(out, out_size);
        return;
    }

    const dim3 b256(256), b32x8(32, 8);

    transpose_bf16<<<dim3(32, 32),  b32x8, 0, stream>>>(Wq, wtQKVG,               1024, 1024);
    transpose_bf16<<<dim3(32, 32),  b32x8, 0, stream>>>(Wk, wtQKVG + 1024 * 1024, 1024, 1024);
    transpose_bf16<<<dim3(32, 32),  b32x8, 0, stream>>>(Wv, wtQKVG + 2048 * 1024, 1024, 1024);
    transpose_bf16<<<dim3(32, 32),  b32x8, 0, stream>>>(Wg, wtQKVG + 3072 * 1024, 1024, 1024);
    transpose_bf16<<<dim3(32, 32),  b32x8, 0, stream>>>(Wo, wtWo,                 1024, 1024);
    transpose_bf16<<<dim3(32, 128), b32x8, 0, stream>>>(W1, wtW1,                 1024, 4096);
    transpose_bf16<<<dim3(128, 32), b32x8, 0, stream>>>(W2, wtW2,                 4096, 1024);

    ln_bf16<<<dim3(8192), b256, 0, stream>>>(x, ln1w, ln1b, xnb);
    gemm_bt<1><<<dim3(64, 24), b256, 0, stream>>>(xnb, wtQKVG, nullptr, qkvb, nullptr, nullptr, 8192, 3072, 1024);
    gemm_bt<0><<<dim3(64, 8),  b256, 0, stream>>>(xnb, wtQKVG + 3072 * 1024, gbuf, nullptr, nullptr, nullptr, 8192, 1024, 1024);

    gla_a<<<dim3(2048), b256, 0, stream>>>(qkvb, gbuf, bg, qdecb, kvT, cdbuf, ointra);
    gla_scan<<<dim3(512), b256, 0, stream>>>(kvT, cdbuf, STb);
    gla_b<<<dim3(2048), b256, 0, stream>>>(qdecb, STb, ointra, obf);

    gemm_bt<2><<<dim3(64, 8), b256, 0, stream>>>(obf, wtWo, x2, nullptr, nullptr, x, 8192, 1024, 1024);
    ln_bf16<<<dim3(8192), b256, 0, stream>>>(x2, ln2w, ln2b, hbf);
    gemm_bt<3><<<dim3(64, 32), b256, 0, stream>>>(hbf, wtW1, nullptr, ffnb, b1, nullptr, 8192, 4096, 1024);
    gemm_bt<4><<<dim3(64, 8),  b256, 0, stream>>>(ffnb, wtW2, out, nullptr, b2, x2, 8192, 1024, 4096);
}